// Round 2
// baseline (3005.695 us; speedup 1.0000x reference)
//
#include <hip/hip_runtime.h>
#include <math.h>

#define T_TOK 8192
#define HDIM 2048
#define IDIM 1024
#define NE 8

#define BM 64
#define BN 64
#define BK 32

typedef __attribute__((ext_vector_type(8))) short short8;

__device__ inline float bf2f(unsigned short u) {
  unsigned v = (unsigned)u << 16;
  return __builtin_bit_cast(float, v);
}
__device__ inline unsigned short f2bf(float f) {
  unsigned u = __builtin_bit_cast(unsigned, f);
  unsigned lsb = (u >> 16) & 1;
  u += 0x7fffu + lsb;  // round-nearest-even
  return (unsigned short)(u >> 16);
}

// ---------- ws layout (bytes) ----------
// 0      : unsigned cnt[8]
// 64     : unsigned cursor[8]
// 128    : unsigned offsets[8]
// 256    : int   sel[2T]              (64 KB)
// 65792  : float wt[2T]               (64 KB)
// 131328 : int   slot_token[2T]       (64 KB)
// 196864 : float slot_w[2T]           (64 KB)
// 263168 : bf16  act[2T * IDIM]       (32 MB)
// total  : 33,817,600 bytes (~32.3 MB)

// ---------------- K0: zero output region + counters ----------------
__global__ __launch_bounds__(256) void k0_zero(float* __restrict__ out,
                                               unsigned* __restrict__ cnt) {
  size_t i = (size_t)blockIdx.x * blockDim.x + threadIdx.x;
  size_t n4 = (size_t)T_TOK * HDIM / 4;
  float4* o4 = (float4*)out;
  float4 z = make_float4(0.f, 0.f, 0.f, 0.f);
  for (size_t p = i; p < n4; p += (size_t)gridDim.x * blockDim.x) o4[p] = z;
  if (blockIdx.x == 0 && threadIdx.x < 24) cnt[threadIdx.x] = 0;  // cnt+cursor+offsets
}

// ---------------- K1: router (one wave per token) ----------------
__global__ __launch_bounds__(256) void k1_router(const float* __restrict__ x,
                                                 const float* __restrict__ wgate,
                                                 float* __restrict__ logits_out,
                                                 int* __restrict__ sel,
                                                 float* __restrict__ wt,
                                                 unsigned* __restrict__ cnt) {
  int wave = threadIdx.x >> 6;
  int lane = threadIdx.x & 63;
  int t = blockIdx.x * 4 + wave;
  float acc[NE];
#pragma unroll
  for (int e = 0; e < NE; ++e) acc[e] = 0.f;
  const float4* xr = (const float4*)(x + (size_t)t * HDIM);
#pragma unroll
  for (int c = 0; c < HDIM / 256; ++c) {
    float4 xv = xr[c * 64 + lane];
    int h = (c * 64 + lane) * 4;
    const float xs[4] = {xv.x, xv.y, xv.z, xv.w};
#pragma unroll
    for (int j = 0; j < 4; ++j) {
      const float* wrow = wgate + (size_t)(h + j) * NE;
#pragma unroll
      for (int e = 0; e < NE; ++e) acc[e] += xs[j] * wrow[e];
    }
  }
#pragma unroll
  for (int e = 0; e < NE; ++e) {
    float v = acc[e];
#pragma unroll
    for (int off = 32; off; off >>= 1) v += __shfl_xor(v, off, 64);
    acc[e] = v;
  }
  if (lane == 0) {
    float m = acc[0];
#pragma unroll
    for (int e = 0; e < NE; ++e) {
      logits_out[(size_t)t * NE + e] = acc[e];
      m = fmaxf(m, acc[e]);
    }
    float p[NE];
#pragma unroll
    for (int e = 0; e < NE; ++e) p[e] = expf(acc[e] - m);
    int b0 = 0;
    float v0 = p[0];
#pragma unroll
    for (int e = 1; e < NE; ++e)
      if (p[e] > v0) { v0 = p[e]; b0 = e; }
    int b1 = -1;
    float v1 = -1.f;
#pragma unroll
    for (int e = 0; e < NE; ++e)
      if (e != b0 && p[e] > v1) { v1 = p[e]; b1 = e; }
    float denom = v0 + v1;
    sel[t * 2 + 0] = b0;
    sel[t * 2 + 1] = b1;
    wt[t * 2 + 0] = v0 / denom;
    wt[t * 2 + 1] = v1 / denom;
    atomicAdd(&cnt[b0], 1u);
    atomicAdd(&cnt[b1], 1u);
  }
}

// ---------------- K2: prefix sum over 8 experts ----------------
__global__ void k2_prefix(const unsigned* __restrict__ cnt,
                          unsigned* __restrict__ offsets,
                          unsigned* __restrict__ cursor) {
  if (threadIdx.x == 0) {
    unsigned s = 0;
    for (int e = 0; e < NE; ++e) {
      offsets[e] = s;
      s += cnt[e];
    }
  }
  if (threadIdx.x < NE) cursor[threadIdx.x] = 0;
}

// ---------------- K3: slot assignment ----------------
__global__ __launch_bounds__(256) void k3_assign(const int* __restrict__ sel,
                                                 const float* __restrict__ wt,
                                                 const unsigned* __restrict__ offsets,
                                                 unsigned* __restrict__ cursor,
                                                 int* __restrict__ slot_token,
                                                 float* __restrict__ slot_w) {
  int t = blockIdx.x * 256 + threadIdx.x;
#pragma unroll
  for (int k = 0; k < 2; ++k) {
    int e = sel[t * 2 + k];
    unsigned p = atomicAdd(&cursor[e], 1u);
    unsigned s = offsets[e] + p;
    slot_token[s] = t;
    slot_w[s] = wt[t * 2 + k];
  }
}

// ---------------- K4: fused gate+up GEMM + silu, bf16 act out ----------------
__global__ __launch_bounds__(256) void k4_gateup(const float* __restrict__ x,
                                                 const float* __restrict__ wg_all,
                                                 const float* __restrict__ wu_all,
                                                 const int* __restrict__ slot_token,
                                                 const unsigned* __restrict__ offsets,
                                                 const unsigned* __restrict__ cnt,
                                                 unsigned short* __restrict__ act) {
  int e = blockIdx.z;
  unsigned n = cnt[e];
  unsigned row0 = blockIdx.y * BM;
  if (row0 >= n) return;
  unsigned base = offsets[e];
  int col0 = blockIdx.x * BN;
  const float* Wg = wg_all + (size_t)e * HDIM * IDIM;
  const float* Wu = wu_all + (size_t)e * HDIM * IDIM;

  __shared__ float Ast[BK][BM];  // transposed A tile: [k][m]
  __shared__ float Bgs[BK][BN];
  __shared__ float Bus[BK][BN];

  int tid = threadIdx.x;
  int am = tid >> 2;
  int ak = (tid & 3) * 4;
  bool arow_valid = (row0 + am) < n;
  const float* xrow = nullptr;
  if (arow_valid) xrow = x + (size_t)slot_token[base + row0 + am] * HDIM;
  int bk = tid >> 4;
  int bn = (tid & 15) * 4;

  int tc4 = (tid & 15) * 4;
  int tr4 = (tid >> 4) * 4;

  float accg[4][4] = {};
  float accu[4][4] = {};
  float4 z4 = make_float4(0.f, 0.f, 0.f, 0.f);

  for (int kt = 0; kt < HDIM / BK; ++kt) {
    int k0 = kt * BK;
    float4 a0 = z4, a1 = z4;
    if (arow_valid) {
      a0 = *(const float4*)(xrow + k0 + ak);
      a1 = *(const float4*)(xrow + k0 + ak + 16);
    }
    const float* gp = Wg + (size_t)(k0 + bk) * IDIM + col0 + bn;
    const float* up = Wu + (size_t)(k0 + bk) * IDIM + col0 + bn;
    float4 bg0 = *(const float4*)gp;
    float4 bg1 = *(const float4*)(gp + (size_t)16 * IDIM);
    float4 bu0 = *(const float4*)up;
    float4 bu1 = *(const float4*)(up + (size_t)16 * IDIM);

    __syncthreads();
    Ast[ak + 0][am] = a0.x;
    Ast[ak + 1][am] = a0.y;
    Ast[ak + 2][am] = a0.z;
    Ast[ak + 3][am] = a0.w;
    Ast[ak + 16][am] = a1.x;
    Ast[ak + 17][am] = a1.y;
    Ast[ak + 18][am] = a1.z;
    Ast[ak + 19][am] = a1.w;
    *(float4*)&Bgs[bk][bn] = bg0;
    *(float4*)&Bgs[bk + 16][bn] = bg1;
    *(float4*)&Bus[bk][bn] = bu0;
    *(float4*)&Bus[bk + 16][bn] = bu1;
    __syncthreads();

#pragma unroll
    for (int k = 0; k < BK; ++k) {
      float4 a = *(const float4*)&Ast[k][tr4];
      float4 bg = *(const float4*)&Bgs[k][tc4];
      float4 bu = *(const float4*)&Bus[k][tc4];
      const float av[4] = {a.x, a.y, a.z, a.w};
      const float bgv[4] = {bg.x, bg.y, bg.z, bg.w};
      const float buv[4] = {bu.x, bu.y, bu.z, bu.w};
#pragma unroll
      for (int i = 0; i < 4; ++i)
#pragma unroll
        for (int j = 0; j < 4; ++j) {
          accg[i][j] += av[i] * bgv[j];
          accu[i][j] += av[i] * buv[j];
        }
    }
  }

  unsigned rows_left = n - row0;
#pragma unroll
  for (int i = 0; i < 4; ++i) {
    int m = tr4 + i;
    if ((unsigned)m < rows_left) {
      size_t slot = base + row0 + m;
      unsigned short* arow = act + slot * IDIM + col0 + tc4;
      ushort4 r;
      float g, u, v;
      g = accg[i][0]; u = accu[i][0]; v = (g / (1.f + expf(-g))) * u; r.x = f2bf(v);
      g = accg[i][1]; u = accu[i][1]; v = (g / (1.f + expf(-g))) * u; r.y = f2bf(v);
      g = accg[i][2]; u = accu[i][2]; v = (g / (1.f + expf(-g))) * u; r.z = f2bf(v);
      g = accg[i][3]; u = accu[i][3]; v = (g / (1.f + expf(-g))) * u; r.w = f2bf(v);
      *(ushort4*)arow = r;
    }
  }
}

// ---------------- K5: down GEMM (bf16 act in) + weighted atomic combine ----------------
__global__ __launch_bounds__(256) void k5_down(const unsigned short* __restrict__ act,
                                               const float* __restrict__ wd_all,
                                               const int* __restrict__ slot_token,
                                               const float* __restrict__ slot_w,
                                               const unsigned* __restrict__ offsets,
                                               const unsigned* __restrict__ cnt,
                                               float* __restrict__ out) {
  int e = blockIdx.z;
  unsigned n = cnt[e];
  unsigned row0 = blockIdx.y * BM;
  if (row0 >= n) return;
  unsigned base = offsets[e];
  int col0 = blockIdx.x * BN;
  const float* Wd = wd_all + (size_t)e * IDIM * HDIM;

  __shared__ float Ast[BK][BM];
  __shared__ float Bs[BK][BN];

  int tid = threadIdx.x;
  // A tile: 64 rows x 32 bf16 (64 B/row) -> 4 threads/row, 8 bf16 (16 B) each
  int am = tid >> 2;
  int ak8 = (tid & 3) * 8;
  bool arow_valid = (row0 + am) < n;
  const unsigned short* arow_g = nullptr;
  if (arow_valid) arow_g = act + (size_t)(base + row0 + am) * IDIM;
  int bk = tid >> 4;
  int bn = (tid & 15) * 4;

  int tc4 = (tid & 15) * 4;
  int tr4 = (tid >> 4) * 4;

  float acc[4][4] = {};

  for (int kt = 0; kt < IDIM / BK; ++kt) {
    int k0 = kt * BK;
    short8 a8 = {};
    if (arow_valid) a8 = *(const short8*)(arow_g + k0 + ak8);
    const float* dp = Wd + (size_t)(k0 + bk) * HDIM + col0 + bn;
    float4 b0 = *(const float4*)dp;
    float4 b1 = *(const float4*)(dp + (size_t)16 * HDIM);

    __syncthreads();
#pragma unroll
    for (int j = 0; j < 8; ++j) Ast[ak8 + j][am] = bf2f((unsigned short)a8[j]);
    *(float4*)&Bs[bk][bn] = b0;
    *(float4*)&Bs[bk + 16][bn] = b1;
    __syncthreads();

#pragma unroll
    for (int k = 0; k < BK; ++k) {
      float4 a = *(const float4*)&Ast[k][tr4];
      float4 b = *(const float4*)&Bs[k][tc4];
      const float av[4] = {a.x, a.y, a.z, a.w};
      const float bv[4] = {b.x, b.y, b.z, b.w};
#pragma unroll
      for (int i = 0; i < 4; ++i)
#pragma unroll
        for (int j = 0; j < 4; ++j) acc[i][j] += av[i] * bv[j];
    }
  }

  unsigned rows_left = n - row0;
#pragma unroll
  for (int i = 0; i < 4; ++i) {
    int m = tr4 + i;
    if ((unsigned)m < rows_left) {
      size_t slot = base + row0 + m;
      int token = slot_token[slot];
      float w = slot_w[slot];
      float* orow = out + (size_t)token * HDIM + col0 + tc4;
#pragma unroll
      for (int j = 0; j < 4; ++j) atomicAdd(&orow[j], w * acc[i][j]);
    }
  }
}

extern "C" void kernel_launch(void* const* d_in, const int* in_sizes, int n_in,
                              void* d_out, int out_size, void* d_ws, size_t ws_size,
                              hipStream_t stream) {
  const float* x = (const float*)d_in[0];      // [T, H]
  const float* wgate = (const float*)d_in[1];  // [H, E]
  const float* wg = (const float*)d_in[2];     // [E, H, I]
  const float* wu = (const float*)d_in[3];     // [E, H, I]
  const float* wd = (const float*)d_in[4];     // [E, I, H]
  float* out = (float*)d_out;
  float* logits = out + (size_t)T_TOK * HDIM;

  // ws footprint guard: refuse to run (loud failure) rather than write OOB.
  const size_t ACT_OFF = 263168;
  const size_t NEED = ACT_OFF + (size_t)2 * T_TOK * IDIM * 2;  // ~32.3 MB
  if (ws_size < NEED) return;

  char* ws = (char*)d_ws;
  unsigned* cnt = (unsigned*)(ws + 0);
  unsigned* cursor = (unsigned*)(ws + 64);
  unsigned* offsets = (unsigned*)(ws + 128);
  int* sel = (int*)(ws + 256);
  float* wt = (float*)(ws + 65792);
  int* slot_token = (int*)(ws + 131328);
  float* slot_w = (float*)(ws + 196864);
  unsigned short* act = (unsigned short*)(ws + ACT_OFF);

  k0_zero<<<2048, 256, 0, stream>>>(out, cnt);
  k1_router<<<T_TOK / 4, 256, 0, stream>>>(x, wgate, logits, sel, wt, cnt);
  k2_prefix<<<1, 64, 0, stream>>>(cnt, offsets, cursor);
  k3_assign<<<T_TOK / 256, 256, 0, stream>>>(sel, wt, offsets, cursor, slot_token, slot_w);
  k4_gateup<<<dim3(IDIM / BN, T_TOK / BM, NE), 256, 0, stream>>>(x, wg, wu, slot_token, offsets,
                                                                 cnt, act);
  k5_down<<<dim3(HDIM / BN, T_TOK / BM, NE), 256, 0, stream>>>(act, wd, slot_token, slot_w,
                                                               offsets, cnt, out);
}

// Round 3
// 1112.703 us; speedup vs baseline: 2.7013x; 2.7013x over previous
//
#include <hip/hip_runtime.h>
#include <math.h>

#define T_TOK 8192
#define HDIM 2048
#define IDIM 1024
#define NE 8

typedef __attribute__((ext_vector_type(8))) short short8;
typedef __attribute__((ext_vector_type(4))) float f32x4;

__device__ inline unsigned short f2bf(float f) {
  unsigned u = __builtin_bit_cast(unsigned, f);
  u += 0x7fffu + ((u >> 16) & 1);  // round-nearest-even
  return (unsigned short)(u >> 16);
}

// B_lds layout: [n][40 u16] rows (80 B, b128-aligned). 16-B granule g holds
// k = 8g..8g+7, stored at granule position g ^ ((n>>2)&3)  (bijective swizzle,
// keeps b128 reads aligned, spreads staging-write banks).
__device__ inline int boff(int nrow, int granule) {  // u16 offset
  return nrow * 40 + 8 * (granule ^ ((nrow >> 2) & 3));
}

// ---------- ws layout (bytes) ----------
// 0      : unsigned cnt[8]
// 64     : unsigned cursor[8]
// 128    : unsigned offsets[8]
// 256    : int   sel[2T]
// 65792  : float wt[2T]
// 131328 : int   slot_token[2T]
// 196864 : float slot_w[2T]
// 263168 : bf16  act[2T * IDIM]   (32 MB)   total ~32.3 MB

// ---------------- K0: zero output region + counters ----------------
__global__ __launch_bounds__(256) void k0_zero(float* __restrict__ out,
                                               unsigned* __restrict__ cnt) {
  size_t i = (size_t)blockIdx.x * blockDim.x + threadIdx.x;
  size_t n4 = (size_t)T_TOK * HDIM / 4;
  float4* o4 = (float4*)out;
  float4 z = make_float4(0.f, 0.f, 0.f, 0.f);
  for (size_t p = i; p < n4; p += (size_t)gridDim.x * blockDim.x) o4[p] = z;
  if (blockIdx.x == 0 && threadIdx.x < 24) cnt[threadIdx.x] = 0;
}

// ---------------- K1: router (one wave per token) ----------------
__global__ __launch_bounds__(256) void k1_router(const float* __restrict__ x,
                                                 const float* __restrict__ wgate,
                                                 float* __restrict__ logits_out,
                                                 int* __restrict__ sel,
                                                 float* __restrict__ wt,
                                                 unsigned* __restrict__ cnt) {
  int wave = threadIdx.x >> 6;
  int lane = threadIdx.x & 63;
  int t = blockIdx.x * 4 + wave;
  float acc[NE];
#pragma unroll
  for (int e = 0; e < NE; ++e) acc[e] = 0.f;
  const float4* xr = (const float4*)(x + (size_t)t * HDIM);
#pragma unroll
  for (int c = 0; c < HDIM / 256; ++c) {
    float4 xv = xr[c * 64 + lane];
    int h = (c * 64 + lane) * 4;
    const float xs[4] = {xv.x, xv.y, xv.z, xv.w};
#pragma unroll
    for (int j = 0; j < 4; ++j) {
      const float* wrow = wgate + (size_t)(h + j) * NE;
#pragma unroll
      for (int e = 0; e < NE; ++e) acc[e] += xs[j] * wrow[e];
    }
  }
#pragma unroll
  for (int e = 0; e < NE; ++e) {
    float v = acc[e];
#pragma unroll
    for (int off = 32; off; off >>= 1) v += __shfl_xor(v, off, 64);
    acc[e] = v;
  }
  if (lane == 0) {
    float m = acc[0];
#pragma unroll
    for (int e = 0; e < NE; ++e) {
      logits_out[(size_t)t * NE + e] = acc[e];
      m = fmaxf(m, acc[e]);
    }
    float p[NE];
#pragma unroll
    for (int e = 0; e < NE; ++e) p[e] = expf(acc[e] - m);
    int b0 = 0;
    float v0 = p[0];
#pragma unroll
    for (int e = 1; e < NE; ++e)
      if (p[e] > v0) { v0 = p[e]; b0 = e; }
    int b1 = -1;
    float v1 = -1.f;
#pragma unroll
    for (int e = 0; e < NE; ++e)
      if (e != b0 && p[e] > v1) { v1 = p[e]; b1 = e; }
    float denom = v0 + v1;
    sel[t * 2 + 0] = b0;
    sel[t * 2 + 1] = b1;
    wt[t * 2 + 0] = v0 / denom;
    wt[t * 2 + 1] = v1 / denom;
    atomicAdd(&cnt[b0], 1u);
    atomicAdd(&cnt[b1], 1u);
  }
}

// ---------------- K2: prefix sum over 8 experts ----------------
__global__ void k2_prefix(const unsigned* __restrict__ cnt,
                          unsigned* __restrict__ offsets,
                          unsigned* __restrict__ cursor) {
  if (threadIdx.x == 0) {
    unsigned s = 0;
    for (int e = 0; e < NE; ++e) {
      offsets[e] = s;
      s += cnt[e];
    }
  }
  if (threadIdx.x < NE) cursor[threadIdx.x] = 0;
}

// ---------------- K3: slot assignment ----------------
__global__ __launch_bounds__(256) void k3_assign(const int* __restrict__ sel,
                                                 const float* __restrict__ wt,
                                                 const unsigned* __restrict__ offsets,
                                                 unsigned* __restrict__ cursor,
                                                 int* __restrict__ slot_token,
                                                 float* __restrict__ slot_w) {
  int t = blockIdx.x * 256 + threadIdx.x;
#pragma unroll
  for (int k = 0; k < 2; ++k) {
    int e = sel[t * 2 + k];
    unsigned p = atomicAdd(&cursor[e], 1u);
    unsigned s = offsets[e] + p;
    slot_token[s] = t;
    slot_w[s] = wt[t * 2 + k];
  }
}

// ---------------- K4: MFMA gate+up GEMM + silu -> bf16 act ----------------
// tile 128m x 64n, 4 waves (wave tile 64x32), K-step 32
__global__ __launch_bounds__(256) void k4_gateup(
    const float* __restrict__ x, const float* __restrict__ wg_all,
    const float* __restrict__ wu_all, const int* __restrict__ slot_token,
    const unsigned* __restrict__ offsets, const unsigned* __restrict__ cnt,
    unsigned short* __restrict__ act) {
  int e = blockIdx.z;
  unsigned n = cnt[e];
  unsigned row0 = blockIdx.x * 128;
  if (row0 >= n) return;
  unsigned base = offsets[e];
  int col0 = blockIdx.y * 64;
  const float* Wg = wg_all + (size_t)e * HDIM * IDIM;
  const float* Wu = wu_all + (size_t)e * HDIM * IDIM;

  __shared__ unsigned short lA[128 * 40];
  __shared__ unsigned short lBg[64 * 40];
  __shared__ unsigned short lBu[64 * 40];

  int tid = threadIdx.x;

  // A staging: 4 rows/thread (r = (tid>>3)+32i), 4 floats at k-quad tid&7
  const float* aptr[4];
#pragma unroll
  for (int i = 0; i < 4; ++i) {
    unsigned grow = row0 + (tid >> 3) + 32 * i;
    unsigned slot = base + (grow < n ? grow : 0);
    aptr[i] = x + (size_t)slot_token[slot] * HDIM + (tid & 7) * 4;
  }
  // B staging: threads 0-127 -> gate, 128-255 -> up. tt: kgrp=tt>>4 (k=4*kgrp..+3),
  // n4=tt&15 (n=4*n4..+3)
  int tt = tid & 127;
  int kgrp = tt >> 4;
  int n4 = tt & 15;
  const float* wsrc =
      ((tid >> 7) ? Wu : Wg) + (size_t)(4 * kgrp) * IDIM + col0 + 4 * n4;
  unsigned short* ldst = (tid >> 7) ? lBu : lBg;

  int wid = tid >> 6, lane = tid & 63;
  int wr = wid >> 1, wc = wid & 1;
  int lr = lane & 15, g = lane >> 4;

  f32x4 accg[4][2] = {};
  f32x4 accu[4][2] = {};

  for (int kt = 0; kt < HDIM / 32; ++kt) {
    int k0 = kt * 32;
    float4 av[4];
#pragma unroll
    for (int i = 0; i < 4; ++i) av[i] = *(const float4*)(aptr[i] + k0);
    float4 bv[4];
#pragma unroll
    for (int r = 0; r < 4; ++r)
      bv[r] = *(const float4*)(wsrc + (size_t)(k0 + r) * IDIM);

    __syncthreads();
    {
      int kq = tid & 7;
#pragma unroll
      for (int i = 0; i < 4; ++i) {
        int r = (tid >> 3) + 32 * i;
        ushort4 w = make_ushort4(f2bf(av[i].x), f2bf(av[i].y), f2bf(av[i].z), f2bf(av[i].w));
        *(ushort4*)&lA[r * 40 + 4 * kq] = w;
      }
    }
    {
      float vals[4][4] = {{bv[0].x, bv[0].y, bv[0].z, bv[0].w},
                          {bv[1].x, bv[1].y, bv[1].z, bv[1].w},
                          {bv[2].x, bv[2].y, bv[2].z, bv[2].w},
                          {bv[3].x, bv[3].y, bv[3].z, bv[3].w}};
      int p = kgrp >> 1, h = kgrp & 1;
#pragma unroll
      for (int i = 0; i < 4; ++i) {
        int nn = 4 * n4 + i;
        ushort4 w = make_ushort4(f2bf(vals[0][i]), f2bf(vals[1][i]), f2bf(vals[2][i]),
                                 f2bf(vals[3][i]));
        *(ushort4*)&ldst[boff(nn, p) + 4 * h] = w;
      }
    }
    __syncthreads();

    short8 af[4];
#pragma unroll
    for (int mf = 0; mf < 4; ++mf)
      af[mf] = *(const short8*)&lA[(wr * 64 + mf * 16 + lr) * 40 + 8 * g];
#pragma unroll
    for (int nf = 0; nf < 2; ++nf) {
      int col = wc * 32 + nf * 16 + lr;
      short8 bg = *(const short8*)&lBg[boff(col, g)];
      short8 bu = *(const short8*)&lBu[boff(col, g)];
#pragma unroll
      for (int mf = 0; mf < 4; ++mf) {
        accg[mf][nf] =
            __builtin_amdgcn_mfma_f32_16x16x32_bf16(af[mf], bg, accg[mf][nf], 0, 0, 0);
        accu[mf][nf] =
            __builtin_amdgcn_mfma_f32_16x16x32_bf16(af[mf], bu, accu[mf][nf], 0, 0, 0);
      }
    }
  }

  unsigned rows_left = n - row0;
#pragma unroll
  for (int mf = 0; mf < 4; ++mf)
#pragma unroll
    for (int nf = 0; nf < 2; ++nf)
#pragma unroll
      for (int j = 0; j < 4; ++j) {
        int rin = wr * 64 + mf * 16 + 4 * g + j;
        if ((unsigned)rin < rows_left) {
          size_t slot = base + row0 + rin;
          int col = col0 + wc * 32 + nf * 16 + lr;
          float gg = accg[mf][nf][j];
          float uu = accu[mf][nf][j];
          float v = (gg / (1.f + expf(-gg))) * uu;
          act[slot * IDIM + col] = f2bf(v);
        }
      }
}

// ---------------- K5: MFMA down GEMM + weighted atomic combine ----------------
// tile 128m x 128n, 4 waves (wave tile 64x64), K-step 32
__global__ __launch_bounds__(256) void k5_down(
    const unsigned short* __restrict__ act, const float* __restrict__ wd_all,
    const int* __restrict__ slot_token, const float* __restrict__ slot_w,
    const unsigned* __restrict__ offsets, const unsigned* __restrict__ cnt,
    float* __restrict__ out) {
  int e = blockIdx.z;
  unsigned n = cnt[e];
  unsigned row0 = blockIdx.x * 128;
  if (row0 >= n) return;
  unsigned base = offsets[e];
  int col0 = blockIdx.y * 128;
  const float* Wd = wd_all + (size_t)e * IDIM * HDIM;

  __shared__ unsigned short lA[128 * 40];
  __shared__ unsigned short lBd[128 * 40];

  int tid = threadIdx.x;

  // A staging (bf16 act): rows r = (tid>>2)+64i, 16B chunk c = tid&3
  const unsigned short* aptr[2];
#pragma unroll
  for (int i = 0; i < 2; ++i) {
    unsigned grow = row0 + (tid >> 2) + 64 * i;
    unsigned slot = base + (grow < n ? grow : 0);
    aptr[i] = act + (size_t)slot * IDIM + (tid & 3) * 8;
  }
  // B staging: kgrp = tid>>5 (k=4*kgrp..+3), nq = tid&31 (n=4*nq..+3)
  int kgrp = tid >> 5;
  int nq = tid & 31;
  const float* wsrc = Wd + (size_t)(4 * kgrp) * HDIM + col0 + 4 * nq;

  int wid = tid >> 6, lane = tid & 63;
  int wr = wid >> 1, wc = wid & 1;
  int lr = lane & 15, g = lane >> 4;

  f32x4 acc[4][4] = {};

  for (int kt = 0; kt < IDIM / 32; ++kt) {
    int k0 = kt * 32;
    short8 av[2];
#pragma unroll
    for (int i = 0; i < 2; ++i) av[i] = *(const short8*)(aptr[i] + k0);
    float4 bv[4];
#pragma unroll
    for (int r = 0; r < 4; ++r)
      bv[r] = *(const float4*)(wsrc + (size_t)(k0 + r) * HDIM);

    __syncthreads();
    {
      int c = tid & 3;
#pragma unroll
      for (int i = 0; i < 2; ++i) {
        int r = (tid >> 2) + 64 * i;
        *(short8*)&lA[r * 40 + 8 * c] = av[i];
      }
    }
    {
      float vals[4][4] = {{bv[0].x, bv[0].y, bv[0].z, bv[0].w},
                          {bv[1].x, bv[1].y, bv[1].z, bv[1].w},
                          {bv[2].x, bv[2].y, bv[2].z, bv[2].w},
                          {bv[3].x, bv[3].y, bv[3].z, bv[3].w}};
      int p = kgrp >> 1, h = kgrp & 1;
#pragma unroll
      for (int i = 0; i < 4; ++i) {
        int nn = 4 * nq + i;
        ushort4 w = make_ushort4(f2bf(vals[0][i]), f2bf(vals[1][i]), f2bf(vals[2][i]),
                                 f2bf(vals[3][i]));
        *(ushort4*)&lBd[boff(nn, p) + 4 * h] = w;
      }
    }
    __syncthreads();

    short8 af[4];
#pragma unroll
    for (int mf = 0; mf < 4; ++mf)
      af[mf] = *(const short8*)&lA[(wr * 64 + mf * 16 + lr) * 40 + 8 * g];
#pragma unroll
    for (int nf = 0; nf < 4; ++nf) {
      int col = wc * 64 + nf * 16 + lr;
      short8 bd = *(const short8*)&lBd[boff(col, g)];
#pragma unroll
      for (int mf = 0; mf < 4; ++mf)
        acc[mf][nf] = __builtin_amdgcn_mfma_f32_16x16x32_bf16(af[mf], bd, acc[mf][nf], 0, 0, 0);
    }
  }

  unsigned rows_left = n - row0;
#pragma unroll
  for (int mf = 0; mf < 4; ++mf)
#pragma unroll
    for (int j = 0; j < 4; ++j) {
      int rin = wr * 64 + mf * 16 + 4 * g + j;
      if ((unsigned)rin < rows_left) {
        size_t slot = base + row0 + rin;
        int token = slot_token[slot];
        float w = slot_w[slot];
        float* orow = out + (size_t)token * HDIM + col0 + wc * 64 + lr;
#pragma unroll
        for (int nf = 0; nf < 4; ++nf)
          atomicAdd(&orow[nf * 16], w * acc[mf][nf][j]);
      }
    }
}

extern "C" void kernel_launch(void* const* d_in, const int* in_sizes, int n_in,
                              void* d_out, int out_size, void* d_ws, size_t ws_size,
                              hipStream_t stream) {
  const float* x = (const float*)d_in[0];
  const float* wgate = (const float*)d_in[1];
  const float* wg = (const float*)d_in[2];
  const float* wu = (const float*)d_in[3];
  const float* wd = (const float*)d_in[4];
  float* out = (float*)d_out;
  float* logits = out + (size_t)T_TOK * HDIM;

  const size_t ACT_OFF = 263168;
  const size_t NEED = ACT_OFF + (size_t)2 * T_TOK * IDIM * 2;
  if (ws_size < NEED) return;  // loud failure instead of OOB corruption

  char* ws = (char*)d_ws;
  unsigned* cnt = (unsigned*)(ws + 0);
  unsigned* cursor = (unsigned*)(ws + 64);
  unsigned* offsets = (unsigned*)(ws + 128);
  int* sel = (int*)(ws + 256);
  float* wt = (float*)(ws + 65792);
  int* slot_token = (int*)(ws + 131328);
  float* slot_w = (float*)(ws + 196864);
  unsigned short* act = (unsigned short*)(ws + ACT_OFF);

  k0_zero<<<2048, 256, 0, stream>>>(out, cnt);
  k1_router<<<T_TOK / 4, 256, 0, stream>>>(x, wgate, logits, sel, wt, cnt);
  k2_prefix<<<1, 64, 0, stream>>>(cnt, offsets, cursor);
  k3_assign<<<T_TOK / 256, 256, 0, stream>>>(sel, wt, offsets, cursor, slot_token, slot_w);
  k4_gateup<<<dim3(T_TOK / 128, IDIM / 64, NE), 256, 0, stream>>>(
      x, wg, wu, slot_token, offsets, cnt, act);
  k5_down<<<dim3(T_TOK / 128, HDIM / 128, NE), 256, 0, stream>>>(
      act, wd, slot_token, slot_w, offsets, cnt, out);
}